// Round 1
// baseline (823.461 us; speedup 1.0000x reference)
//
#include <hip/hip_runtime.h>

#define IN_F 64
#define HID_F 128
#define CHUNK 4096 // edges per partition block
#define CAPB 4096  // per-bucket buffer capacity (avg fill ~2046, >40 sigma safe)
#define MAXB 512   // >= NBUCK = ceil(N/128)
#define AGS 68     // LDS agg row stride in floats: 68%32=4 -> edge rows land on
                   // rotated banks (atomics <=2-way), 272B rows stay 16B-aligned

typedef unsigned short u16;
typedef unsigned int u32;
typedef _Float16 f16;
typedef __attribute__((ext_vector_type(4))) _Float16 f16x4;
typedef __attribute__((ext_vector_type(8))) _Float16 f16x8;
typedef __attribute__((ext_vector_type(4))) float f32x4;

// ---------------------------------------------------------------------------
// Pass 1: partition edges into 128-node buckets (by dst for aggregation, by
// src for out-degree). LDS histogram -> per-block global reservation -> plain
// scattered stores into per-bucket regions. No per-edge global atomics.
// Last block instead converts W1/W2 to transposed fp16 (fused prep).
// ---------------------------------------------------------------------------
__global__ __launch_bounds__(256)
void partition_kernel(const int* __restrict__ src, const int* __restrict__ dst,
                      int* __restrict__ gcurD, int* __restrict__ gcurS,
                      u32* __restrict__ bufD, u16* __restrict__ bufS,
                      const float* __restrict__ W1, const float* __restrict__ W2,
                      f16* __restrict__ W1t, f16* __restrict__ W2t,
                      int E, int NBUCK) {
    if (blockIdx.x == gridDim.x - 1) {
        for (int t = threadIdx.x; t < 2 * IN_F * HID_F; t += 256) {
            if (t < IN_F * HID_F) {
                int n = t / IN_F, k = t % IN_F;
                W1t[t] = (f16)W1[k * HID_F + n];
            } else {
                int i = t - IN_F * HID_F;
                int n = i / HID_F, k = i % HID_F;
                W2t[i] = (f16)W2[k * IN_F + n];
            }
        }
        return;
    }
    __shared__ int histD[MAXB], histS[MAXB], baseD[MAXB], baseS[MAXB];
    const int t  = threadIdx.x;
    const int e0 = blockIdx.x * CHUNK;
    const int n  = min(CHUNK, E - e0);

    for (int b = t; b < NBUCK; b += 256) { histD[b] = 0; histS[b] = 0; }
    __syncthreads();
    for (int i = t; i < n; i += 256) {
        atomicAdd(&histD[dst[e0 + i] >> 7], 1);
        atomicAdd(&histS[src[e0 + i] >> 7], 1);
    }
    __syncthreads();
    for (int b = t; b < NBUCK; b += 256) {
        baseD[b] = atomicAdd(&gcurD[b], histD[b]);
        baseS[b] = atomicAdd(&gcurS[b], histS[b]);
        histD[b] = 0;  // reuse as running cursors
        histS[b] = 0;
    }
    __syncthreads();
    for (int i = t; i < n; i += 256) {
        int d  = dst[e0 + i];
        int s  = src[e0 + i];
        int bD = d >> 7, bS = s >> 7;
        int p  = baseD[bD] + atomicAdd(&histD[bD], 1);
        if (p < CAPB) bufD[(size_t)bD * CAPB + p] = (u32)d | ((u32)s << 16);
        int p2 = baseS[bS] + atomicAdd(&histS[bS], 1);
        if (p2 < CAPB) bufS[(size_t)bS * CAPB + p2] = (u16)s;
    }
}

// ---------------------------------------------------------------------------
// Pass 2: per src-bucket: out-degree histogram -> norm_src + fp16 prescale of
// this bucket's 128 in_feat rows (scaled_x = (f16)(x * ns)). The old dst-side
// slot-CSR build is GONE (aggregation now consumes bufD directly).
// ---------------------------------------------------------------------------
__global__ __launch_bounds__(256)
void srcnorm_prescale_kernel(const u16* __restrict__ bufS, const int* __restrict__ gcurS,
                             float* __restrict__ norm_src,
                             const float* __restrict__ x, f16x4* __restrict__ scaled_x,
                             int N) {
    __shared__ int lcur[128];
    const int t = threadIdx.x;
    if (t < 128) lcur[t] = 0;
    __syncthreads();
    const int b = blockIdx.x;
    const int cnt = min(gcurS[b], CAPB);
    const u16* p = bufS + (size_t)b * CAPB;
    for (int i = t; i < cnt; i += 256)
        atomicAdd(&lcur[p[i] & 127], 1);
    __syncthreads();
    const int node0 = b * 128;
    if (t < 128 && node0 + t < N)
        norm_src[node0 + t] = rsqrtf((float)max(lcur[t], 1));
    for (int i = t; i < 128 * 16; i += 256) {
        int r = i >> 4, c = i & 15;
        int node = node0 + r;
        if (node < N) {
            float nsv = rsqrtf((float)max(lcur[r], 1));
            float4 v = ((const float4*)x)[(size_t)node * 16 + c];
            f16x4 h;
            h.x = (f16)(v.x * nsv); h.y = (f16)(v.y * nsv);
            h.z = (f16)(v.z * nsv); h.w = (f16)(v.w * nsv);
            scaled_x[(size_t)node * 16 + c] = h;
        }
    }
}

// ---------------------------------------------------------------------------
// Layer 1+2 GEMM, one 128-node dst-bucket per block:
//   edge-parallel LDS fp32 aggregation of scaled_x over bufD (ds_add_f32),
//   deg count folded in (-> norm_dst), then per-16-row tiles:
//   h = relu((agg @ W1)*nd + b1)  ->  g2 = (h @ W2)*ns   (both MFMA, f16)
// Thread layout for edges: 32 edges x 8 f16x8-chunks, 8-deep unrolled.
// bufD reads coalesced; each x-row read = 128B burst by 8 lanes.
// ---------------------------------------------------------------------------
__global__ __launch_bounds__(256)
void agg_gemm_kernel(const u32* __restrict__ bufD, const int* __restrict__ gcurD,
                     const f16x8* __restrict__ xs,
                     const f16* __restrict__ W1t, const float* __restrict__ b1,
                     const float* __restrict__ ns, float* __restrict__ norm_dst,
                     const f16* __restrict__ W2t, f16* __restrict__ g2, int N) {
    constexpr int LDH = HID_F + 8;  // 136 f16 = 272 B
    __shared__ float sAgg[128 * AGS];                 // 34816 B
    __shared__ __align__(16) f16 h[2][16 * LDH];      // 8704 B, ping-pong
    __shared__ int sCnt[128];
    __shared__ float sNd[128], sNs[128];

    const int t = threadIdx.x;
    const int b = blockIdx.x;
    const int node0 = b * 128;

    for (int i = t; i < 128 * AGS; i += 256) sAgg[i] = 0.f;
    if (t < 128) sCnt[t] = 0;
    __syncthreads();

    const int cnt = min(gcurD[b], CAPB);
    const u32* p = bufD + (size_t)b * CAPB;
    const int c  = t & 7;    // f16x8 chunk (16B) within 128B row
    const int el = t >> 3;   // 0..31 edge lane

    for (int base = 0; base < cnt; base += 256) {
        u32 v[8];
        f16x8 xv[8];
#pragma unroll
        for (int j = 0; j < 8; ++j) {
            int idx = base + el + j * 32;
            v[j] = (idx < cnt) ? p[idx] : 0xFFFFFFFFu;
        }
#pragma unroll
        for (int j = 0; j < 8; ++j)
            if (v[j] != 0xFFFFFFFFu)
                xv[j] = xs[(size_t)(v[j] >> 16) * 8 + c];
#pragma unroll
        for (int j = 0; j < 8; ++j)
            if (v[j] != 0xFFFFFFFFu) {
                int dl = v[j] & 127;
                if (c == 0) atomicAdd(&sCnt[dl], 1);
                float* a = &sAgg[dl * AGS + c * 8];
#pragma unroll
                for (int k = 0; k < 8; ++k)
                    atomicAdd(&a[k], (float)xv[j][k]);
            }
    }
    __syncthreads();

    if (t < 128) {
        int node = node0 + t;
        float ndv = rsqrtf((float)max(sCnt[t], 1));
        sNd[t] = ndv;
        if (node < N) norm_dst[node] = ndv;
        sNs[t] = (node < N) ? ns[node] : 1.f;
    }
    __syncthreads();

    const int wave = t >> 6;
    const int lane = t & 63;
    const int nl   = lane & 15;
    const int quad = lane >> 4;

    for (int rt = 0; rt < 8; ++rt) {
        // ---- stage 1: wave w -> h cols {2w,2w+1}, rows rt*16..rt*16+15 ----
        f16x8 a1[2];
#pragma unroll
        for (int kf = 0; kf < 2; ++kf) {
            const float* ap = &sAgg[(rt * 16 + nl) * AGS + kf * 32 + quad * 8];
            f16x8 av;
#pragma unroll
            for (int k = 0; k < 8; ++k) av[k] = (f16)ap[k];
            a1[kf] = av;
        }
        float rs1[4];
#pragma unroll
        for (int reg = 0; reg < 4; ++reg)
            rs1[reg] = sNd[rt * 16 + quad * 4 + reg];

        f16* hb = h[rt & 1];
#pragma unroll
        for (int cti = 0; cti < 2; ++cti) {
            const int ct = wave * 2 + cti;
            f32x4 acc1 = (f32x4){0.f, 0.f, 0.f, 0.f};
#pragma unroll
            for (int kf = 0; kf < 2; ++kf) {
                f16x8 bf = *(const f16x8*)(W1t + (ct * 16 + nl) * IN_F + kf * 32 + quad * 8);
                acc1 = __builtin_amdgcn_mfma_f32_16x16x32_f16(a1[kf], bf, acc1, 0, 0, 0);
            }
            float bb = b1[ct * 16 + nl];
#pragma unroll
            for (int reg = 0; reg < 4; ++reg) {
                float vv = fmaxf(acc1[reg] * rs1[reg] + bb, 0.f);
                hb[(quad * 4 + reg) * LDH + ct * 16 + nl] = (f16)vv;
            }
        }
        __syncthreads();  // one barrier per rt: write/read split by ping-pong

        // ---- stage 2: wave w -> g2 cols [16w,16w+16), K = 128 ----
        f32x4 acc2 = (f32x4){0.f, 0.f, 0.f, 0.f};
#pragma unroll
        for (int kf = 0; kf < 4; ++kf) {
            f16x8 a2 = *(const f16x8*)(hb + nl * LDH + kf * 32 + quad * 8);
            f16x8 bf = *(const f16x8*)(W2t + (wave * 16 + nl) * HID_F + kf * 32 + quad * 8);
            acc2 = __builtin_amdgcn_mfma_f32_16x16x32_f16(a2, bf, acc2, 0, 0, 0);
        }
#pragma unroll
        for (int reg = 0; reg < 4; ++reg) {
            int r = node0 + rt * 16 + quad * 4 + reg;
            if (r < N) {
                float rs2 = sNs[rt * 16 + quad * 4 + reg];
                g2[(size_t)r * IN_F + wave * 16 + nl] = (f16)(acc2[reg] * rs2);
            }
        }
    }
}

// ---------------------------------------------------------------------------
// Layer-2 aggregation: edge-parallel LDS fp32 agg of g2 over bufD, then
//   out[n,:] = agg[n,:] * nd[n] + b2   (fp32, float4 stores)
// ---------------------------------------------------------------------------
__global__ __launch_bounds__(256)
void agg_out_kernel(const u32* __restrict__ bufD, const int* __restrict__ gcurD,
                    const f16x8* __restrict__ g2, const float* __restrict__ norm_dst,
                    const float* __restrict__ bias, float4* __restrict__ out, int N) {
    __shared__ float sAgg[128 * AGS];
    __shared__ float sNd[128];
    const int t = threadIdx.x;
    const int b = blockIdx.x;
    const int node0 = b * 128;

    for (int i = t; i < 128 * AGS; i += 256) sAgg[i] = 0.f;
    if (t < 128) sNd[t] = (node0 + t < N) ? norm_dst[node0 + t] : 1.f;
    __syncthreads();

    const int cnt = min(gcurD[b], CAPB);
    const u32* p = bufD + (size_t)b * CAPB;
    const int c  = t & 7;
    const int el = t >> 3;

    for (int base = 0; base < cnt; base += 256) {
        u32 v[8];
        f16x8 xv[8];
#pragma unroll
        for (int j = 0; j < 8; ++j) {
            int idx = base + el + j * 32;
            v[j] = (idx < cnt) ? p[idx] : 0xFFFFFFFFu;
        }
#pragma unroll
        for (int j = 0; j < 8; ++j)
            if (v[j] != 0xFFFFFFFFu)
                xv[j] = g2[(size_t)(v[j] >> 16) * 8 + c];
#pragma unroll
        for (int j = 0; j < 8; ++j)
            if (v[j] != 0xFFFFFFFFu) {
                float* a = &sAgg[(v[j] & 127) * AGS + c * 8];
#pragma unroll
                for (int k = 0; k < 8; ++k)
                    atomicAdd(&a[k], (float)xv[j][k]);
            }
    }
    __syncthreads();

    const int cc = t & 15;
    const float4 bb = ((const float4*)bias)[cc];
    for (int rr = t >> 4; rr < 128; rr += 16) {
        int node = node0 + rr;
        if (node >= N) break;
        float ndv = sNd[rr];
        const float* a = &sAgg[rr * AGS + cc * 4];
        float4 o;
        o.x = a[0] * ndv + bb.x;
        o.y = a[1] * ndv + bb.y;
        o.z = a[2] * ndv + bb.z;
        o.w = a[3] * ndv + bb.w;
        out[(size_t)node * 16 + cc] = o;
    }
}

extern "C" void kernel_launch(void* const* d_in, const int* in_sizes, int n_in,
                              void* d_out, int out_size, void* d_ws, size_t ws_size,
                              hipStream_t stream) {
    const float* in_feat = (const float*)d_in[0];
    const float* W1      = (const float*)d_in[1];
    const float* b1      = (const float*)d_in[2];
    const float* W2      = (const float*)d_in[3];
    const float* b2      = (const float*)d_in[4];
    const int*   src     = (const int*)d_in[5];
    const int*   dst     = (const int*)d_in[6];

    const int N = in_sizes[0] / IN_F;
    const int E = in_sizes[5];
    float* out = (float*)d_out;

    const int NBUCK = (N + 127) >> 7;  // 391 for N=50000

    // workspace (~23 MB):
    // ints:  gcurD[MAXB] | gcurS[MAXB]
    // f32:   norm_src[N] | norm_dst[N]
    // f16:   scaled_x[N*64] | g2[N*64] | W1t[8192] | W2t[8192]
    // u32:   bufD[NBUCK*CAPB] ; u16: bufS[NBUCK*CAPB]
    int* gcurD      = (int*)d_ws;
    int* gcurS      = gcurD + MAXB;
    float* norm_src = (float*)(gcurS + MAXB);
    float* norm_dst = norm_src + N;
    f16* scaled_x   = (f16*)(norm_dst + N);
    f16* g2         = scaled_x + (size_t)N * IN_F;
    f16* W1t        = g2 + (size_t)N * IN_F;
    f16* W2t        = W1t + IN_F * HID_F;
    u32* bufD       = (u32*)(W2t + IN_F * HID_F);
    u16* bufS       = (u16*)(bufD + (size_t)NBUCK * CAPB);

    // ---- 1: bucket partition (no per-edge global atomics) + W prep ----
    hipMemsetAsync(gcurD, 0, sizeof(int) * 2 * MAXB, stream);
    partition_kernel<<<(E + CHUNK - 1) / CHUNK + 1, 256, 0, stream>>>(
        src, dst, gcurD, gcurS, bufD, bufS, W1, W2, W1t, W2t, E, NBUCK);

    // ---- 2: out-degree norms + fp16 prescale (src buckets only) ----
    srcnorm_prescale_kernel<<<NBUCK, 256, 0, stream>>>(
        bufS, gcurS, norm_src, in_feat, (f16x4*)scaled_x, N);

    // ---- 3: edge-parallel LDS agg + double MFMA GEMM per dst bucket ----
    agg_gemm_kernel<<<NBUCK, 256, 0, stream>>>(
        bufD, gcurD, (const f16x8*)scaled_x, W1t, b1, norm_src, norm_dst,
        W2t, g2, N);

    // ---- 4: edge-parallel LDS agg of g2 -> *nd + b2 -> fp32 out ----
    agg_out_kernel<<<NBUCK, 256, 0, stream>>>(
        bufD, gcurD, (const f16x8*)g2, norm_dst, b2, (float4*)out, N);
}

// Round 2
// 167.599 us; speedup vs baseline: 4.9133x; 4.9133x over previous
//
#include <hip/hip_runtime.h>

#define IN_F 64
#define HID_F 128
#define CAP 64     // max in-degree slots per node (Poisson(16): P(>64) ~ 1e-20)
#define CHUNK 4096 // edges per partition block
#define CAPB 4096  // per-bucket buffer capacity (avg fill ~2046, >40 sigma safe)
#define MAXB 512   // >= NBUCK = ceil(N/128)

typedef unsigned short u16;
typedef unsigned int u32;
typedef _Float16 f16;
typedef __attribute__((ext_vector_type(4))) _Float16 f16x4;
typedef __attribute__((ext_vector_type(8))) _Float16 f16x8;
typedef __attribute__((ext_vector_type(4))) float f32x4;

// ---------------------------------------------------------------------------
// Pass 1: partition edges into 128-node buckets (by dst for CSR build, by src
// for out-degree). LDS histogram -> per-block global reservation -> plain
// scattered stores into per-bucket regions. No per-edge global atomics.
// Edges are register-cached between the histogram and scatter passes (single
// global read of src/dst; CHUNK=4096 -> exactly 16 edges/thread, unrolled so
// the arrays stay in VGPRs).
// Last block instead converts W1/W2 to transposed fp16 (fused prep).
// ---------------------------------------------------------------------------
__global__ __launch_bounds__(256)
void partition_kernel(const int* __restrict__ src, const int* __restrict__ dst,
                      int* __restrict__ gcurD, int* __restrict__ gcurS,
                      u32* __restrict__ bufD, u16* __restrict__ bufS,
                      const float* __restrict__ W1, const float* __restrict__ W2,
                      f16* __restrict__ W1t, f16* __restrict__ W2t,
                      int E, int NBUCK) {
    if (blockIdx.x == gridDim.x - 1) {
        for (int t = threadIdx.x; t < 2 * IN_F * HID_F; t += 256) {
            if (t < IN_F * HID_F) {
                int n = t / IN_F, k = t % IN_F;
                W1t[t] = (f16)W1[k * HID_F + n];
            } else {
                int i = t - IN_F * HID_F;
                int n = i / HID_F, k = i % HID_F;
                W2t[i] = (f16)W2[k * IN_F + n];
            }
        }
        return;
    }
    __shared__ int histD[MAXB], histS[MAXB], baseD[MAXB], baseS[MAXB];
    const int t  = threadIdx.x;
    const int e0 = blockIdx.x * CHUNK;
    const int n  = min(CHUNK, E - e0);

    int ed[16], es[16];

    for (int b = t; b < NBUCK; b += 256) { histD[b] = 0; histS[b] = 0; }
    __syncthreads();
#pragma unroll
    for (int j = 0; j < 16; ++j) {
        int i = t + j * 256;
        if (i < n) {
            ed[j] = dst[e0 + i];
            es[j] = src[e0 + i];
            atomicAdd(&histD[ed[j] >> 7], 1);
            atomicAdd(&histS[es[j] >> 7], 1);
        }
    }
    __syncthreads();
    for (int b = t; b < NBUCK; b += 256) {
        baseD[b] = atomicAdd(&gcurD[b], histD[b]);
        baseS[b] = atomicAdd(&gcurS[b], histS[b]);
        histD[b] = 0;  // reuse as running cursors
        histS[b] = 0;
    }
    __syncthreads();
#pragma unroll
    for (int j = 0; j < 16; ++j) {
        int i = t + j * 256;
        if (i < n) {
            int d  = ed[j];
            int s  = es[j];
            int bD = d >> 7, bS = s >> 7;
            int p  = baseD[bD] + atomicAdd(&histD[bD], 1);
            if (p < CAPB) bufD[(size_t)bD * CAPB + p] = (u32)d | ((u32)s << 16);
            int p2 = baseS[bS] + atomicAdd(&histS[bS], 1);
            if (p2 < CAPB) bufS[(size_t)bS * CAPB + p2] = (u16)s;
        }
    }
}

// ---------------------------------------------------------------------------
// Pass 2 (merged, + norms + prescale):
//   blocks [0,NBUCK):      slot placement via LDS atomics -> slots, deg_in,
//                          norm_dst (from final LDS counters)
//   blocks [NBUCK,2*NBUCK): src histogram in LDS -> norm_src + fp16 prescale
//                          of this bucket's 128 in_feat rows (scaled_x)
// ---------------------------------------------------------------------------
__global__ __launch_bounds__(256)
void bucket_pass2_kernel(const u32* __restrict__ bufD, const int* __restrict__ gcurD,
                         const u16* __restrict__ bufS, const int* __restrict__ gcurS,
                         u16* __restrict__ slots, int* __restrict__ deg_in,
                         float* __restrict__ norm_dst, float* __restrict__ norm_src,
                         const float* __restrict__ x, f16x4* __restrict__ scaled_x,
                         int N, int NBUCK) {
    __shared__ int lcur[128];
    const int t = threadIdx.x;
    if (t < 128) lcur[t] = 0;
    __syncthreads();
    if (blockIdx.x < NBUCK) {
        const int b = blockIdx.x;
        const int cnt = min(gcurD[b], CAPB);
        const u32* p = bufD + (size_t)b * CAPB;
        for (int i = t; i < cnt; i += 256) {
            u32 v = p[i];
            int d = (int)(v & 0xFFFFu);
            int s = (int)(v >> 16);
            int pos = atomicAdd(&lcur[d & 127], 1);
            if (pos < CAP) slots[(size_t)d * CAP + pos] = (u16)s;
        }
        __syncthreads();
        int node = b * 128 + t;
        if (t < 128 && node < N) {
            deg_in[node]   = lcur[t];
            norm_dst[node] = rsqrtf((float)max(lcur[t], 1));
        }
    } else {
        const int b = blockIdx.x - NBUCK;
        const int cnt = min(gcurS[b], CAPB);
        const u16* p = bufS + (size_t)b * CAPB;
        for (int i = t; i < cnt; i += 256)
            atomicAdd(&lcur[p[i] & 127], 1);
        __syncthreads();
        int node0 = b * 128;
        if (t < 128 && node0 + t < N)
            norm_src[node0 + t] = rsqrtf((float)max(lcur[t], 1));
        // prescale this bucket's 128 rows: scaled_x[n,:] = (f16) x[n,:]*ns
        for (int i = t; i < 128 * 16; i += 256) {
            int r = i >> 4, c = i & 15;
            int node = node0 + r;
            if (node < N) {
                float ns = rsqrtf((float)max(lcur[r], 1));
                float4 v = ((const float4*)x)[(size_t)node * 16 + c];
                f16x4 h;
                h.x = (f16)(v.x * ns); h.y = (f16)(v.y * ns);
                h.z = (f16)(v.z * ns); h.w = (f16)(v.w * ns);
                scaled_x[(size_t)node * 16 + c] = h;
            }
        }
    }
}

// ---------------------------------------------------------------------------
// Fused gather + double MFMA GEMM, one 32-row tile per block (grid = N/32):
//   gather: 256 threads = 32 rows x 8 f16x8-chunks (16B/lane loads — half the
//           load/address-gen instructions of the 16x16 f16x4 layout)
//   stage 1: two 16-row sub-tiles; wave w computes h cols {2w,2w+1} for each
//   stage 2: wave w computes g2 cols ct=w over K=128 for each sub-tile
// LDS ~13.3 KB/block. LDX=72 f16 (144 B), LDH=136 f16 (272 B): all f16x8 LDS
// accesses 16B-aligned.
// ---------------------------------------------------------------------------
__global__ __launch_bounds__(256)
void gather_gemm_kernel(const f16x8* __restrict__ xs, const u16* __restrict__ slots,
                        const int* __restrict__ deg_in,
                        const f16* __restrict__ W1t, const float* __restrict__ b1,
                        const float* __restrict__ nd, const float* __restrict__ ns,
                        const f16* __restrict__ W2t, f16* __restrict__ g2, int N) {
    constexpr int LDX = IN_F + 8;    // 72 f16 = 144 B row stride
    constexpr int LDH = HID_F + 8;   // 136 f16 = 272 B
    __shared__ __align__(16) f16 sx[32 * LDX];
    __shared__ __align__(16) f16 h[2][16 * LDH];

    const int t   = threadIdx.x;
    const int row = t >> 3;          // 0..31
    const int c   = t & 7;           // f16x8 chunk
    const int r0  = blockIdx.x * 32;
    const int node = r0 + row;

    // ---- gather: one (row, chunk) per thread, 8 row-reads in flight ----
    float acc[8];
#pragma unroll
    for (int k = 0; k < 8; ++k) acc[k] = 0.f;
    if (node < N) {
        int deg = min(deg_in[node], CAP);
        const u16* srow = slots + (size_t)node * CAP;
        int i = 0;
        for (; i + 8 <= deg; i += 8) {
            int s[8];
#pragma unroll
            for (int j = 0; j < 8; ++j) s[j] = (int)srow[i + j];
            f16x8 v[8];
#pragma unroll
            for (int j = 0; j < 8; ++j) v[j] = xs[(size_t)s[j] * 8 + c];
#pragma unroll
            for (int j = 0; j < 8; ++j)
#pragma unroll
                for (int k = 0; k < 8; ++k) acc[k] += (float)v[j][k];
        }
        for (; i < deg; ++i) {
            f16x8 v = xs[(size_t)srow[i] * 8 + c];
#pragma unroll
            for (int k = 0; k < 8; ++k) acc[k] += (float)v[k];
        }
    }
    {   // stash to LDS tile (zeros for OOB rows)
        f16x8 hv;
#pragma unroll
        for (int k = 0; k < 8; ++k) hv[k] = (f16)acc[k];
        *(f16x8*)&sx[row * LDX + c * 8] = hv;
    }
    __syncthreads();

    const int wave = t >> 6;
    const int lane = t & 63;
    const int nl   = lane & 15;
    const int quad = lane >> 4;

    // ---- stage 1: per sub-tile rt, wave w -> h cols ct = {2w, 2w+1} ----
#pragma unroll
    for (int rt = 0; rt < 2; ++rt) {
        f16x8 a1[2];
#pragma unroll
        for (int kf = 0; kf < 2; ++kf)
            a1[kf] = *(const f16x8*)(sx + (rt * 16 + nl) * LDX + kf * 32 + quad * 8);

        float rs1[4];
#pragma unroll
        for (int reg = 0; reg < 4; ++reg)
            rs1[reg] = nd[min(r0 + rt * 16 + quad * 4 + reg, N - 1)];

        f16* hb = h[rt];
#pragma unroll
        for (int cti = 0; cti < 2; ++cti) {
            const int ct = wave * 2 + cti;
            f32x4 acc1 = (f32x4){0.f, 0.f, 0.f, 0.f};
#pragma unroll
            for (int kf = 0; kf < 2; ++kf) {
                f16x8 b = *(const f16x8*)(W1t + (ct * 16 + nl) * IN_F + kf * 32 + quad * 8);
                acc1 = __builtin_amdgcn_mfma_f32_16x16x32_f16(a1[kf], b, acc1, 0, 0, 0);
            }
            float bb = b1[ct * 16 + nl];
#pragma unroll
            for (int reg = 0; reg < 4; ++reg) {
                float v = fmaxf(acc1[reg] * rs1[reg] + bb, 0.f);
                hb[(quad * 4 + reg) * LDH + ct * 16 + nl] = (f16)v;
            }
        }
    }
    __syncthreads();

    // ---- stage 2: per sub-tile rt, wave w -> g2 cols ct = w, K = 128 ----
#pragma unroll
    for (int rt = 0; rt < 2; ++rt) {
        f32x4 acc2 = (f32x4){0.f, 0.f, 0.f, 0.f};
#pragma unroll
        for (int kf = 0; kf < 4; ++kf) {
            f16x8 a2 = *(const f16x8*)(h[rt] + nl * LDH + kf * 32 + quad * 8);
            f16x8 b  = *(const f16x8*)(W2t + (wave * 16 + nl) * HID_F + kf * 32 + quad * 8);
            acc2 = __builtin_amdgcn_mfma_f32_16x16x32_f16(a2, b, acc2, 0, 0, 0);
        }

        float rs2[4];
#pragma unroll
        for (int reg = 0; reg < 4; ++reg)
            rs2[reg] = ns[min(r0 + rt * 16 + quad * 4 + reg, N - 1)];
#pragma unroll
        for (int reg = 0; reg < 4; ++reg) {
            int r = r0 + rt * 16 + quad * 4 + reg;
            if (r < N)
                g2[(size_t)r * IN_F + wave * 16 + nl] = (f16)(acc2[reg] * rs2[reg]);
        }
    }
}

// ---------------------------------------------------------------------------
// Gather-aggregate with fp32 epilogue to d_out:
//   out[n,:] = (sum_{s in nbrs(n)} g2[s,:]) * nd[n] + b2
// 8 lanes per node, f16x8 (16B) gather loads.
// ---------------------------------------------------------------------------
__global__ __launch_bounds__(256)
void gather_out_kernel(const f16x8* __restrict__ xs, const u16* __restrict__ slots,
                       const int* __restrict__ deg_in, const float* __restrict__ sd,
                       const float* __restrict__ bias,
                       float4* __restrict__ out, int N) {
    int tg = blockIdx.x * blockDim.x + threadIdx.x;
    int node = tg >> 3;
    int c = tg & 7;
    if (node >= N) return;
    int deg = min(deg_in[node], CAP);
    const u16* srow = slots + (size_t)node * CAP;
    float acc[8];
#pragma unroll
    for (int k = 0; k < 8; ++k) acc[k] = 0.f;

    int i = 0;
    for (; i + 8 <= deg; i += 8) {
        int s[8];
#pragma unroll
        for (int j = 0; j < 8; ++j) s[j] = (int)srow[i + j];
        f16x8 v[8];
#pragma unroll
        for (int j = 0; j < 8; ++j) v[j] = xs[(size_t)s[j] * 8 + c];
#pragma unroll
        for (int j = 0; j < 8; ++j)
#pragma unroll
            for (int k = 0; k < 8; ++k) acc[k] += (float)v[j][k];
    }
    for (; i < deg; ++i) {
        f16x8 v = xs[(size_t)srow[i] * 8 + c];
#pragma unroll
        for (int k = 0; k < 8; ++k) acc[k] += (float)v[k];
    }
    float d = sd[node];
    float4 b0 = ((const float4*)bias)[c * 2];
    float4 b1v = ((const float4*)bias)[c * 2 + 1];
    float4 o0, o1;
    o0.x = acc[0] * d + b0.x;  o0.y = acc[1] * d + b0.y;
    o0.z = acc[2] * d + b0.z;  o0.w = acc[3] * d + b0.w;
    o1.x = acc[4] * d + b1v.x; o1.y = acc[5] * d + b1v.y;
    o1.z = acc[6] * d + b1v.z; o1.w = acc[7] * d + b1v.w;
    out[(size_t)node * 16 + c * 2]     = o0;
    out[(size_t)node * 16 + c * 2 + 1] = o1;
}

extern "C" void kernel_launch(void* const* d_in, const int* in_sizes, int n_in,
                              void* d_out, int out_size, void* d_ws, size_t ws_size,
                              hipStream_t stream) {
    const float* in_feat = (const float*)d_in[0];
    const float* W1      = (const float*)d_in[1];
    const float* b1      = (const float*)d_in[2];
    const float* W2      = (const float*)d_in[3];
    const float* b2      = (const float*)d_in[4];
    const int*   src     = (const int*)d_in[5];
    const int*   dst     = (const int*)d_in[6];

    const int N = in_sizes[0] / IN_F;
    const int E = in_sizes[5];
    float* out = (float*)d_out;

    const int NBUCK = (N + 127) >> 7;  // 391 for N=50000

    // workspace (~29 MB):
    // ints:  deg_in[N] | gcurD[MAXB] | gcurS[MAXB]
    // u16:   slots[N*CAP]
    // f32:   norm_src[N] | norm_dst[N]
    // f16:   scaled_x[N*64] | g2[N*64] | W1t[8192] | W2t[8192]
    // u32:   bufD[NBUCK*CAPB] ; u16: bufS[NBUCK*CAPB]
    int* deg_in  = (int*)d_ws;
    int* gcurD   = deg_in + N;
    int* gcurS   = gcurD + MAXB;
    u16* slots   = (u16*)(gcurS + MAXB);
    float* norm_src = (float*)(slots + (size_t)N * CAP);
    float* norm_dst = norm_src + N;
    f16* scaled_x = (f16*)(norm_dst + N);
    f16* g2       = scaled_x + (size_t)N * IN_F;
    f16* W1t      = g2 + (size_t)N * IN_F;
    f16* W2t      = W1t + IN_F * HID_F;
    u32* bufD     = (u32*)(W2t + IN_F * HID_F);
    u16* bufS     = (u16*)(bufD + (size_t)NBUCK * CAPB);

    // ---- 1: bucket partition (no per-edge global atomics) + W prep ----
    hipMemsetAsync(gcurD, 0, sizeof(int) * 2 * MAXB, stream);
    partition_kernel<<<(E + CHUNK - 1) / CHUNK + 1, 256, 0, stream>>>(
        src, dst, gcurD, gcurS, bufD, bufS, W1, W2, W1t, W2t, E, NBUCK);

    // ---- 2: slots + deg_in + norms + fp16 prescale (one dispatch) ----
    bucket_pass2_kernel<<<2 * NBUCK, 256, 0, stream>>>(
        bufD, gcurD, bufS, gcurS, slots, deg_in, norm_dst, norm_src,
        in_feat, (f16x4*)scaled_x, N, NBUCK);

    // ---- 3: gather + double MFMA GEMM, 32 rows/block (agg1 never global) ----
    gather_gemm_kernel<<<(N + 31) / 32, 256, 0, stream>>>(
        (const f16x8*)scaled_x, slots, deg_in, W1t, b1, norm_dst, norm_src,
        W2t, g2, N);

    // ---- 4: final gather (*norm_dst + b2) -> fp32 out ----
    gather_out_kernel<<<(N * 8 + 255) / 256, 256, 0, stream>>>(
        (const f16x8*)g2, slots, deg_in, norm_dst, b2, (float4*)out, N);
}